// Round 1
// baseline (1520.643 us; speedup 1.0000x reference)
//
#include <hip/hip_runtime.h>

#define NBATCH 64
#define SRCLEN 2048
#define DIMK 1024
#define MROWS (NBATCH * SRCLEN) /* 131072 */

typedef __attribute__((ext_vector_type(4))) float f32x4;
typedef __attribute__((ext_vector_type(8))) short bf16x8;

#define AS_GLOBAL __attribute__((address_space(1)))
#define AS_LDS __attribute__((address_space(3)))

// ---- fp32 -> packed bf16 pair (RNE). gfx950 has v_cvt_pk_bf16_f32. ----
__device__ __forceinline__ int cvt_pk_bf16(float a, float b) {
#if __has_builtin(__builtin_amdgcn_cvt_pk_bf16_f32)
  auto p = __builtin_amdgcn_cvt_pk_bf16_f32(a, b);
  return __builtin_bit_cast(int, p);
#else
  unsigned ua = __float_as_uint(a), ub = __float_as_uint(b);
  ua = (ua + 0x7fffu + ((ua >> 16) & 1u)) >> 16;
  ub = (ub + 0x7fffu + ((ub >> 16) & 1u)) & 0xffff0000u;
  return (int)(ua | ub);
#endif
}

// tanh(x) = 1 - 2/(exp2(x*2/ln2)+1); saturates gracefully at +-1 (inf -> rcp -> 0)
__device__ __forceinline__ float fast_tanh(float x) {
#if __has_builtin(__builtin_amdgcn_exp2f) && __has_builtin(__builtin_amdgcn_rcpf)
  float e = __builtin_amdgcn_exp2f(x * 2.885390081777927f);
  return 1.0f - 2.0f * __builtin_amdgcn_rcpf(e + 1.0f);
#else
  float cx = fminf(15.f, fmaxf(-15.f, x));
  float e = __expf(2.0f * cx);
  return (e - 1.0f) / (e + 1.0f);
#endif
}

// ---------------- K0a: W_context fp32 -> bf16 (row-major [n][k]) ----------------
__global__ __launch_bounds__(256) void cvt_wc_kernel(const float* __restrict__ W,
                                                     unsigned short* __restrict__ Wb) {
  int i = (blockIdx.x * 256 + threadIdx.x) * 4;
  f32x4 x = *(const f32x4*)(W + i);
  int2 o;
  o.x = cvt_pk_bf16(x[0], x[1]);
  o.y = cvt_pk_bf16(x[2], x[3]);
  *(int2*)(Wb + i) = o;
}

// ---------------- K0b: bias[b][n] = src@Wq^T + cond@Wcd^T + bq ----------------
__global__ __launch_bounds__(128) void bias_kernel(
    const float* __restrict__ src, const float* __restrict__ cond,
    const float* __restrict__ Wq, const float* __restrict__ bq,
    const float* __restrict__ Wcd, float* __restrict__ biasOut) {
  const int b = blockIdx.y, nb = blockIdx.x, tid = threadIdx.x;
  __shared__ float sl[1024], cl[1024];
#pragma unroll
  for (int r = 0; r < 8; ++r) {
    sl[(r << 7) + tid] = src[(b << 10) + (r << 7) + tid];
    cl[(r << 7) + tid] = cond[(b << 10) + (r << 7) + tid];
  }
  __syncthreads();
  const int n = (nb << 7) + tid;
  const float* wq = Wq + (size_t)n * DIMK;
  const float* wc = Wcd + (size_t)n * DIMK;
  float aq = 0.f, ac = 0.f;
  for (int k = 0; k < DIMK; k += 4) {
    f32x4 s4 = *(const f32x4*)(sl + k);
    f32x4 c4 = *(const f32x4*)(cl + k);
    f32x4 q4 = *(const f32x4*)(wq + k);
    f32x4 w4 = *(const f32x4*)(wc + k);
    aq += s4[0] * q4[0] + s4[1] * q4[1] + s4[2] * q4[2] + s4[3] * q4[3];
    ac += c4[0] * w4[0] + c4[1] * w4[1] + c4[2] * w4[2] + c4[3] * w4[3];
  }
  biasOut[(b << 10) + n] = aq + ac + bq[n];
}

// ---------------- KB: fused GEMM + tanh + v-dot -> align partials ----------------
// Tile 128x128, BK=64, 4 waves (2x2 of 64x64), 16x16x32 bf16 MFMA, 4x4 acc/wave.
// A = memory_bank rows (fp32, staged via global_load_lds, converted in-register).
// B = W_context bf16 rows [n][k] (B^T layout, staged via global_load_lds).
__global__ __launch_bounds__(256) void gemm_align_kernel(
    const float* __restrict__ mb, const unsigned short* __restrict__ Wc,
    const float* __restrict__ bias, const float* __restrict__ v,
    float* __restrict__ alignP) {
  __shared__ float As[128 * 64];           // 32 KiB, rows m, packed (stride 64 f32)
  __shared__ unsigned short Bs[128 * 64];  // 16 KiB, rows n, packed (stride 64 bf16)
  __shared__ float red[2][128];

  const int tid = threadIdx.x;
  const int lane = tid & 63;
  const int w = tid >> 6;
  const int wm = w & 1, wn = w >> 1;
  const int lr = lane & 15, quad = lane >> 4;
  const int nb = blockIdx.x;
  const int m0 = blockIdx.y << 7;
  const int n0 = nb << 7;

  f32x4 acc[4][4] = {};

  for (int kt = 0; kt < 16; ++kt) {
    // A: 32 instrs of 1 KiB (4 fp32 rows each); wave w issues q = w*8+r
#pragma unroll
    for (int r = 0; r < 8; ++r) {
      int q = (w << 3) + r;
      const float* g = mb + (size_t)(m0 + (q << 2) + (lane >> 4)) * DIMK +
                       (kt << 6) + ((lane & 15) << 2);
      __builtin_amdgcn_global_load_lds((const AS_GLOBAL unsigned*)g,
                                       (AS_LDS unsigned*)(As + q * 256), 16, 0, 0);
    }
    // B: 16 instrs of 1 KiB (8 bf16 rows each); wave w issues q = w*4+r
#pragma unroll
    for (int r = 0; r < 4; ++r) {
      int q = (w << 2) + r;
      const unsigned short* g = Wc + (size_t)(n0 + (q << 3) + (lane >> 3)) * DIMK +
                                (kt << 6) + ((lane & 7) << 3);
      __builtin_amdgcn_global_load_lds((const AS_GLOBAL unsigned*)g,
                                       (AS_LDS unsigned*)(Bs + q * 512), 16, 0, 0);
    }
    __syncthreads();

#pragma unroll
    for (int ks = 0; ks < 2; ++ks) {
      bf16x8 af[4];
#pragma unroll
      for (int i = 0; i < 4; ++i) {
        // A[m = lr + i*16 + wm*64][k = ks*32 + quad*8 .. +8) fp32 -> bf16
        const float* p = As + ((wm << 6) + (i << 4) + lr) * 64 + (ks << 5) + (quad << 3);
        f32x4 lo = *(const f32x4*)p;
        f32x4 hi = *(const f32x4*)(p + 4);
        union { int i4[4]; bf16x8 v8; } u;
        u.i4[0] = cvt_pk_bf16(lo[0], lo[1]);
        u.i4[1] = cvt_pk_bf16(lo[2], lo[3]);
        u.i4[2] = cvt_pk_bf16(hi[0], hi[1]);
        u.i4[3] = cvt_pk_bf16(hi[2], hi[3]);
        af[i] = u.v8;
      }
#pragma unroll
      for (int j = 0; j < 4; ++j) {
        bf16x8 bf = *(const bf16x8*)(Bs + (((wn << 6) + (j << 4) + lr) << 6) +
                                     (ks << 5) + (quad << 3));
#pragma unroll
        for (int i = 0; i < 4; ++i)
          acc[i][j] = __builtin_amdgcn_mfma_f32_16x16x32_bf16(af[i], bf, acc[i][j], 0, 0, 0);
      }
    }
    __syncthreads();
  }

  // Epilogue: u = acc + bias[b][n]; t = tanh(u); partial_align[m] += t * v[n]
  const int b = m0 >> 11;  // 2048 rows per batch, 128 | 2048 -> uniform per block
  float rowsum[4][4] = {};
#pragma unroll
  for (int j = 0; j < 4; ++j) {
    int n = n0 + (wn << 6) + (j << 4) + lr;  // D col = lane&15
    float bn = bias[(b << 10) + n];
    float vn = v[n];
#pragma unroll
    for (int i = 0; i < 4; ++i)
#pragma unroll
      for (int rg = 0; rg < 4; ++rg) {
        float t = fast_tanh(acc[i][j][rg] + bn);
        rowsum[i][rg] = fmaf(t, vn, rowsum[i][rg]);
      }
  }
  // sum over the 16 columns held across lanes lr=0..15 (same quad)
#pragma unroll
  for (int xm = 1; xm < 16; xm <<= 1)
#pragma unroll
    for (int i = 0; i < 4; ++i)
#pragma unroll
      for (int rg = 0; rg < 4; ++rg)
        rowsum[i][rg] += __shfl_xor(rowsum[i][rg], xm, 64);
  if (lr == 0) {
#pragma unroll
    for (int i = 0; i < 4; ++i)
#pragma unroll
      for (int rg = 0; rg < 4; ++rg)
        red[wn][(wm << 6) + (i << 4) + (quad << 2) + rg] = rowsum[i][rg];
  }
  __syncthreads();
  if (tid < 128)
    alignP[(size_t)nb * MROWS + m0 + tid] = red[0][tid] + red[1][tid];
}

// ---------------- KC: softmax over s per batch; writes output 1 ----------------
__global__ __launch_bounds__(256) void softmax_kernel(const float* __restrict__ alignP,
                                                      float* __restrict__ outA) {
  const int b = blockIdx.x, tid = threadIdx.x;
  float loc[8];
  float mx = -3.0e38f;
#pragma unroll
  for (int r = 0; r < 8; ++r) {
    int s = (r << 8) + tid;
    float a = 0.f;
#pragma unroll
    for (int q = 0; q < 8; ++q) a += alignP[(size_t)q * MROWS + (b << 11) + s];
    loc[r] = a;
    mx = fmaxf(mx, a);
  }
#pragma unroll
  for (int o = 32; o > 0; o >>= 1) mx = fmaxf(mx, __shfl_xor(mx, o, 64));
  __shared__ float sred[8];
  if ((tid & 63) == 0) sred[tid >> 6] = mx;
  __syncthreads();
  mx = fmaxf(fmaxf(sred[0], sred[1]), fmaxf(sred[2], sred[3]));
  float sum = 0.f;
#pragma unroll
  for (int r = 0; r < 8; ++r) {
    loc[r] = __expf(loc[r] - mx);
    sum += loc[r];
  }
#pragma unroll
  for (int o = 32; o > 0; o >>= 1) sum += __shfl_xor(sum, o, 64);
  __syncthreads();
  if ((tid & 63) == 0) sred[4 + (tid >> 6)] = sum;
  __syncthreads();
  sum = sred[4] + sred[5] + sred[6] + sred[7];
  float inv = 1.0f / sum;
#pragma unroll
  for (int r = 0; r < 8; ++r) outA[(b << 11) + (r << 8) + tid] = loc[r] * inv;
}

// ---------------- KD: context partials c_chunk[b][d] = sum_s w*h ----------------
__global__ __launch_bounds__(256) void ctx_partial_kernel(const float* __restrict__ mb,
                                                          const float* __restrict__ wgt,
                                                          float* __restrict__ cP) {
  const int chunk = blockIdx.x, b = blockIdx.y, tid = threadIdx.x;
  __shared__ float wl[128];
  if (tid < 128) wl[tid] = wgt[(b << 11) + (chunk << 7) + tid];
  __syncthreads();
  const float* base = mb + ((size_t)(b << 11) + (chunk << 7)) * DIMK + (tid << 2);
  f32x4 a = {0.f, 0.f, 0.f, 0.f};
  for (int s = 0; s < 128; ++s) {
    f32x4 m4 = *(const f32x4*)(base + (size_t)s * DIMK);
    a += m4 * wl[s];
  }
  *(f32x4*)(cP + ((size_t)((chunk << 6) + b) << 10) + (tid << 2)) = a;
}

// ---------------- KE: reduce 16 chunks -> c (output 0) ----------------
__global__ __launch_bounds__(256) void ctx_reduce_kernel(const float* __restrict__ cP,
                                                         float* __restrict__ out) {
  int idx = blockIdx.x * 256 + threadIdx.x;
  float s = 0.f;
#pragma unroll
  for (int c = 0; c < 16; ++c) s += cP[(c << 16) + idx];
  out[idx] = s;
}

extern "C" void kernel_launch(void* const* d_in, const int* in_sizes, int n_in,
                              void* d_out, int out_size, void* d_ws, size_t ws_size,
                              hipStream_t stream) {
  const float* source = (const float*)d_in[0];
  const float* mb = (const float*)d_in[1];
  const float* cond = (const float*)d_in[2];
  const float* Wq = (const float*)d_in[3];
  const float* bq = (const float*)d_in[4];
  const float* Wc = (const float*)d_in[5];
  const float* Wcd = (const float*)d_in[6];
  const float* v = (const float*)d_in[7];
  float* out = (float*)d_out;

  // ws layout: Wc_bf16 2 MiB | bias 256 KiB | alignP 4 MiB | cP 4 MiB  (~10.25 MiB)
  char* ws = (char*)d_ws;
  unsigned short* Wc_bf = (unsigned short*)ws;
  float* bias = (float*)(ws + (2u << 20));
  float* alignP = (float*)(ws + (2u << 20) + (256u << 10));
  float* cP = (float*)(ws + (2u << 20) + (256u << 10) + (4u << 20));

  cvt_wc_kernel<<<1024, 256, 0, stream>>>(Wc, Wc_bf);
  bias_kernel<<<dim3(8, 64), 128, 0, stream>>>(source, cond, Wq, bq, Wcd, bias);
  gemm_align_kernel<<<dim3(8, 1024), 256, 0, stream>>>(mb, Wc_bf, bias, v, alignP);
  softmax_kernel<<<64, 256, 0, stream>>>(alignP, out + NBATCH * DIMK);
  ctx_partial_kernel<<<dim3(16, 64), 256, 0, stream>>>(mb, out + NBATCH * DIMK, cP);
  ctx_reduce_kernel<<<256, 256, 0, stream>>>(cP, out);
}

// Round 2
// 1144.890 us; speedup vs baseline: 1.3282x; 1.3282x over previous
//
#include <hip/hip_runtime.h>

#define NBATCH 64
#define SRCLEN 2048
#define DIMK 1024
#define MROWS (NBATCH * SRCLEN) /* 131072 */
#define NNB 4                   /* n-blocks of 256 */

typedef __attribute__((ext_vector_type(4))) float f32x4;
typedef __attribute__((ext_vector_type(8))) short bf16x8;

#define AS_GLOBAL __attribute__((address_space(1)))
#define AS_LDS __attribute__((address_space(3)))

__device__ __forceinline__ int cvt_pk_bf16(float a, float b) {
#if __has_builtin(__builtin_amdgcn_cvt_pk_bf16_f32)
  auto p = __builtin_amdgcn_cvt_pk_bf16_f32(a, b);
  return __builtin_bit_cast(int, p);
#else
  unsigned ua = __float_as_uint(a), ub = __float_as_uint(b);
  ua = (ua + 0x7fffu + ((ua >> 16) & 1u)) >> 16;
  ub = (ub + 0x7fffu + ((ub >> 16) & 1u)) & 0xffff0000u;
  return (int)(ua | ub);
#endif
}

__device__ __forceinline__ float fast_tanh(float x) {
#if __has_builtin(__builtin_amdgcn_exp2f) && __has_builtin(__builtin_amdgcn_rcpf)
  float e = __builtin_amdgcn_exp2f(x * 2.885390081777927f);
  return 1.0f - 2.0f * __builtin_amdgcn_rcpf(e + 1.0f);
#else
  float cx = fminf(15.f, fmaxf(-15.f, x));
  float e = __expf(2.0f * cx);
  return (e - 1.0f) / (e + 1.0f);
#endif
}

// ---------------- K0a: W_context fp32 -> bf16 (row-major [n][k]) ----------------
__global__ __launch_bounds__(256) void cvt_wc_kernel(const float* __restrict__ W,
                                                     unsigned short* __restrict__ Wb) {
  int i = (blockIdx.x * 256 + threadIdx.x) * 4;
  f32x4 x = *(const f32x4*)(W + i);
  int2 o;
  o.x = cvt_pk_bf16(x[0], x[1]);
  o.y = cvt_pk_bf16(x[2], x[3]);
  *(int2*)(Wb + i) = o;
}

// ---------------- K0b: bias[b][n] = src@Wq^T + cond@Wcd^T + bq ----------------
// Wave-per-row: 64 lanes read one W row coalesced (16 f32 each), shuffle-reduce.
__global__ __launch_bounds__(256) void bias_kernel(
    const float* __restrict__ src, const float* __restrict__ cond,
    const float* __restrict__ Wq, const float* __restrict__ bq,
    const float* __restrict__ Wcd, float* __restrict__ biasOut) {
  const int b = blockIdx.y, nb = blockIdx.x, tid = threadIdx.x;
  const int w = tid >> 6, lane = tid & 63;
  __shared__ float sl[1024], cl[1024];
  *(f32x4*)(sl + (tid << 2)) = *(const f32x4*)(src + (b << 10) + (tid << 2));
  *(f32x4*)(cl + (tid << 2)) = *(const f32x4*)(cond + (b << 10) + (tid << 2));
  __syncthreads();
  f32x4 s4[4], c4[4];
#pragma unroll
  for (int u = 0; u < 4; ++u) {
    s4[u] = *(const f32x4*)(sl + (lane << 4) + (u << 2));
    c4[u] = *(const f32x4*)(cl + (lane << 4) + (u << 2));
  }
  for (int it = 0; it < 32; ++it) {
    const int n = (nb << 7) + (w << 5) + it;
    const float* wq = Wq + (size_t)n * DIMK + (lane << 4);
    const float* wc = Wcd + (size_t)n * DIMK + (lane << 4);
    float a = 0.f;
#pragma unroll
    for (int u = 0; u < 4; ++u) {
      f32x4 q4 = *(const f32x4*)(wq + (u << 2));
      f32x4 w4 = *(const f32x4*)(wc + (u << 2));
      a += q4[0] * s4[u][0] + q4[1] * s4[u][1] + q4[2] * s4[u][2] + q4[3] * s4[u][3];
      a += w4[0] * c4[u][0] + w4[1] * c4[u][1] + w4[2] * c4[u][2] + w4[3] * c4[u][3];
    }
#pragma unroll
    for (int xm = 1; xm < 64; xm <<= 1) a += __shfl_xor(a, xm, 64);
    if (lane == 0) biasOut[(b << 10) + n] = a + bq[n];
  }
}

// ---------------- KB: fused GEMM + tanh + v-dot -> align partials ----------------
// Block tile 128m x 256n, BK=64, 4 waves (2x2) each 64m x 128n, 16x16x32 bf16 MFMA.
// LDS XOR-swizzled: A (fp32, 16B chunk c of row r at c^(r&15)), B (bf16, c^(r&7)).
// global_load_lds lane->chunk permutation realizes the swizzle at stage time.
__global__ __launch_bounds__(256, 2) void gemm_align_kernel(
    const float* __restrict__ mb, const unsigned short* __restrict__ Wc,
    const float* __restrict__ bias, const float* __restrict__ v,
    float* __restrict__ alignP) {
  __shared__ float As[128 * 64];           // 32 KiB, swizzled
  __shared__ unsigned short Bs[256 * 64];  // 32 KiB, swizzled
  __shared__ float red[2][128];

  const int tid = threadIdx.x;
  const int lane = tid & 63;
  const int w = tid >> 6;
  const int wm = w & 1, wn = w >> 1;
  const int lr = lane & 15, quad = lane >> 4;
  const int nb = blockIdx.x;
  const int m0 = blockIdx.y << 7;
  const int n0 = nb << 8;

  f32x4 acc[4][8] = {};

  for (int kt = 0; kt < 16; ++kt) {
    // A: 32 x 1KiB instrs (4 fp32 rows each); global chunk = (lane&15) ^ (row&15)
#pragma unroll
    for (int r = 0; r < 8; ++r) {
      int q = (w << 3) + r;
      int row = (q << 2) + (lane >> 4);
      int c = (lane & 15) ^ (row & 15);
      const float* g = mb + (size_t)(m0 + row) * DIMK + (kt << 6) + (c << 2);
      __builtin_amdgcn_global_load_lds((const AS_GLOBAL unsigned*)g,
                                       (AS_LDS unsigned*)(As + q * 256), 16, 0, 0);
    }
    // B: 32 x 1KiB instrs (8 bf16 rows each); global chunk = (lane&7) ^ (lane>>3)
#pragma unroll
    for (int r = 0; r < 8; ++r) {
      int q = (w << 3) + r;
      int row = (q << 3) + (lane >> 3);
      int c = (lane & 7) ^ (lane >> 3);
      const unsigned short* g = Wc + (size_t)(n0 + row) * DIMK + (kt << 6) + (c << 3);
      __builtin_amdgcn_global_load_lds((const AS_GLOBAL unsigned*)g,
                                       (AS_LDS unsigned*)(Bs + q * 512), 16, 0, 0);
    }
    __syncthreads();

#pragma unroll
    for (int ks = 0; ks < 2; ++ks) {
      bf16x8 af[4];
#pragma unroll
      for (int i = 0; i < 4; ++i) {
        // A[m = wm*64 + i*16 + lr][k = ks*32 + quad*8 ..]; chunks (c, c+1) at (c^lr, (c^lr)^1)
        int row = (wm << 6) + (i << 4) + lr;
        int p0 = ((ks << 3) + (quad << 1)) ^ lr;
        f32x4 lo = *(const f32x4*)(As + (row << 6) + (p0 << 2));
        f32x4 hi = *(const f32x4*)(As + (row << 6) + ((p0 ^ 1) << 2));
        union { int i4[4]; bf16x8 v8; } u;
        u.i4[0] = cvt_pk_bf16(lo[0], lo[1]);
        u.i4[1] = cvt_pk_bf16(lo[2], lo[3]);
        u.i4[2] = cvt_pk_bf16(hi[0], hi[1]);
        u.i4[3] = cvt_pk_bf16(hi[2], hi[3]);
        af[i] = u.v8;
      }
#pragma unroll
      for (int j = 0; j < 8; ++j) {
        int row = (wn << 7) + (j << 4) + lr;
        int pb = ((ks << 2) + quad) ^ (lr & 7);
        bf16x8 bf = *(const bf16x8*)(Bs + (row << 6) + (pb << 3));
#pragma unroll
        for (int i = 0; i < 4; ++i)
          acc[i][j] = __builtin_amdgcn_mfma_f32_16x16x32_bf16(af[i], bf, acc[i][j], 0, 0, 0);
      }
    }
    __syncthreads();
  }

  // Epilogue: t = tanh(acc + bias[b][n]); partial_align[m] += t * v[n]
  const int b = m0 >> 11;  // 128 | 2048 -> uniform per block
  float rowsum[4][4] = {};
#pragma unroll
  for (int j = 0; j < 8; ++j) {
    int n = n0 + (wn << 7) + (j << 4) + lr;  // C/D col = lane&15
    float bn = bias[(b << 10) + n];
    float vn = v[n];
#pragma unroll
    for (int i = 0; i < 4; ++i)
#pragma unroll
      for (int rg = 0; rg < 4; ++rg) {
        float t = fast_tanh(acc[i][j][rg] + bn);
        rowsum[i][rg] = fmaf(t, vn, rowsum[i][rg]);
      }
  }
#pragma unroll
  for (int xm = 1; xm < 16; xm <<= 1)
#pragma unroll
    for (int i = 0; i < 4; ++i)
#pragma unroll
      for (int rg = 0; rg < 4; ++rg)
        rowsum[i][rg] += __shfl_xor(rowsum[i][rg], xm, 64);
  if (lr == 0) {
#pragma unroll
    for (int i = 0; i < 4; ++i)
#pragma unroll
      for (int rg = 0; rg < 4; ++rg)
        red[wn][(wm << 6) + (i << 4) + (quad << 2) + rg] = rowsum[i][rg];
  }
  __syncthreads();
  if (tid < 128)
    alignP[(size_t)nb * MROWS + m0 + tid] = red[0][tid] + red[1][tid];
}

// ---------------- KC: softmax over s per batch; writes output 1 ----------------
__global__ __launch_bounds__(256) void softmax_kernel(const float* __restrict__ alignP,
                                                      float* __restrict__ outA) {
  const int b = blockIdx.x, tid = threadIdx.x;
  float loc[8];
  float mx = -3.0e38f;
#pragma unroll
  for (int r = 0; r < 8; ++r) {
    int s = (r << 8) + tid;
    float a = 0.f;
#pragma unroll
    for (int q = 0; q < NNB; ++q) a += alignP[(size_t)q * MROWS + (b << 11) + s];
    loc[r] = a;
    mx = fmaxf(mx, a);
  }
#pragma unroll
  for (int o = 32; o > 0; o >>= 1) mx = fmaxf(mx, __shfl_xor(mx, o, 64));
  __shared__ float sred[8];
  if ((tid & 63) == 0) sred[tid >> 6] = mx;
  __syncthreads();
  mx = fmaxf(fmaxf(sred[0], sred[1]), fmaxf(sred[2], sred[3]));
  float sum = 0.f;
#pragma unroll
  for (int r = 0; r < 8; ++r) {
    loc[r] = __expf(loc[r] - mx);
    sum += loc[r];
  }
#pragma unroll
  for (int o = 32; o > 0; o >>= 1) sum += __shfl_xor(sum, o, 64);
  __syncthreads();
  if ((tid & 63) == 0) sred[4 + (tid >> 6)] = sum;
  __syncthreads();
  sum = sred[4] + sred[5] + sred[6] + sred[7];
  float inv = 1.0f / sum;
#pragma unroll
  for (int r = 0; r < 8; ++r) outA[(b << 11) + (r << 8) + tid] = loc[r] * inv;
}

// ---------------- KD: context partials c_chunk[b][d] = sum_s w*h ----------------
__global__ __launch_bounds__(256) void ctx_partial_kernel(const float* __restrict__ mb,
                                                          const float* __restrict__ wgt,
                                                          float* __restrict__ cP) {
  const int chunk = blockIdx.x, b = blockIdx.y, tid = threadIdx.x;
  __shared__ float wl[64];
  if (tid < 64) wl[tid] = wgt[(b << 11) + (chunk << 6) + tid];
  __syncthreads();
  const float* base = mb + ((size_t)(b << 11) + (chunk << 6)) * DIMK + (tid << 2);
  f32x4 a = {0.f, 0.f, 0.f, 0.f};
#pragma unroll 4
  for (int s = 0; s < 64; ++s) {
    f32x4 m4 = *(const f32x4*)(base + (size_t)s * DIMK);
    a += m4 * wl[s];
  }
  *(f32x4*)(cP + ((size_t)((chunk << 6) + b) << 10) + (tid << 2)) = a;
}

// ---------------- KE: reduce 32 chunks -> c (output 0) ----------------
__global__ __launch_bounds__(256) void ctx_reduce_kernel(const float* __restrict__ cP,
                                                         float* __restrict__ out) {
  int idx = blockIdx.x * 256 + threadIdx.x;
  float s = 0.f;
#pragma unroll
  for (int c = 0; c < 32; ++c) s += cP[(size_t)(c << 16) + idx];
  out[idx] = s;
}

extern "C" void kernel_launch(void* const* d_in, const int* in_sizes, int n_in,
                              void* d_out, int out_size, void* d_ws, size_t ws_size,
                              hipStream_t stream) {
  const float* source = (const float*)d_in[0];
  const float* mb = (const float*)d_in[1];
  const float* cond = (const float*)d_in[2];
  const float* Wq = (const float*)d_in[3];
  const float* bq = (const float*)d_in[4];
  const float* Wc = (const float*)d_in[5];
  const float* Wcd = (const float*)d_in[6];
  const float* v = (const float*)d_in[7];
  float* out = (float*)d_out;

  // ws: Wc_bf16 2 MiB | bias 256 KiB | alignP 2 MiB | cP 8 MiB
  char* ws = (char*)d_ws;
  unsigned short* Wc_bf = (unsigned short*)ws;
  float* bias = (float*)(ws + (2u << 20));
  float* alignP = (float*)(ws + (2u << 20) + (256u << 10));
  float* cP = (float*)(ws + (4u << 20) + (256u << 10));

  cvt_wc_kernel<<<1024, 256, 0, stream>>>(Wc, Wc_bf);
  bias_kernel<<<dim3(8, 64), 256, 0, stream>>>(source, cond, Wq, bq, Wcd, bias);
  gemm_align_kernel<<<dim3(NNB, 1024), 256, 0, stream>>>(mb, Wc_bf, bias, v, alignP);
  softmax_kernel<<<64, 256, 0, stream>>>(alignP, out + NBATCH * DIMK);
  ctx_partial_kernel<<<dim3(32, 64), 256, 0, stream>>>(mb, out + NBATCH * DIMK, cP);
  ctx_reduce_kernel<<<256, 256, 0, stream>>>(cP, out);
}